// Round 5
// baseline (640.974 us; speedup 1.0000x reference)
//
#include <hip/hip_runtime.h>
#include <hip/hip_bf16.h>

#define BSZ 16384
#define DIM 512
#define NEMB 8192
#define NEG 0.01f
#define NSPLIT 4
#define NG 128   // 8 nt-tiles (256 cols) * 16 kk-steps

typedef __attribute__((ext_vector_type(8))) short short8;
typedef __attribute__((ext_vector_type(4))) float f32x4;
typedef __attribute__((ext_vector_type(16))) float f32x16;

typedef const __attribute__((address_space(1))) void GVT;
typedef __attribute__((address_space(3))) void LVT;

__device__ __forceinline__ void gl_lds16(const void* g, void* l) {
    __builtin_amdgcn_global_load_lds((GVT*)g, (LVT*)l, 16, 0, 0);
}

__device__ __forceinline__ float bf2f(unsigned short u) {
    union { unsigned int i; float f; } c; c.i = ((unsigned int)u) << 16; return c.f;
}
__device__ __forceinline__ unsigned short f2bf(float f) {
    union { __hip_bfloat16 h; unsigned short u; } c; c.h = __float2bfloat16(f); return c.u;
}
// monotone-orderable uint key for a float
__device__ __forceinline__ unsigned int fkey(float f) {
    unsigned int u = __float_as_uint(f);
    return u ^ ((unsigned int)((int)u >> 31) | 0x80000000u);
}

// barrier leaving one tile's 6 DMA loads in flight
__device__ __forceinline__ void pipe_barrier() {
    asm volatile("s_waitcnt vmcnt(6) lgkmcnt(0)\ns_barrier" ::: "memory");
}
__device__ __forceinline__ void plain_barrier() {
    asm volatile("s_barrier" ::: "memory");
}

// 6 async global->LDS loads for tile G (A: 128x32 = 2 instr, B: 256x32 = 4 instr)
#define ISSUE_TILE(G, BUF) do { \
    int Gm = (G) & (NG - 1); \
    int kko = (Gm & 15) << 5; \
    const unsigned short* pa = gA + kko; \
    const unsigned short* pb = gB + ((Gm >> 4) * (256 * DIM)) + kko; \
    gl_lds16(pa,             &sA[BUF][uW]); \
    gl_lds16(pa + 64 * DIM,  &sA[BUF][uW + 2048]); \
    gl_lds16(pb,             &sB[BUF][uW]); \
    gl_lds16(pb + 64 * DIM,  &sB[BUF][uW + 2048]); \
    gl_lds16(pb + 128 * DIM, &sB[BUF][uW + 4096]); \
    gl_lds16(pb + 192 * DIM, &sB[BUF][uW + 6144]); \
} while (0)

// 16 x mfma_32x32x16 on a 64x128 wave tile (2 mi x 4 ni), K=32 (2 halves)
#define COMPUTE_TILE(BUF) do { \
    _Pragma("unroll") for (int kk2 = 0; kk2 < 2; kk2++) { \
        short8 af[2], bfv[4]; \
        _Pragma("unroll") for (int i = 0; i < 2; i++) \
            af[i] = *(const short8*)&sA[BUF][offA[i] + kk2 * 16]; \
        _Pragma("unroll") for (int i = 0; i < 4; i++) \
            bfv[i] = *(const short8*)&sB[BUF][offB[i] + kk2 * 16]; \
        _Pragma("unroll") for (int mi = 0; mi < 2; mi++) \
            _Pragma("unroll") for (int ni = 0; ni < 4; ni++) \
                acc[mi][ni] = __builtin_amdgcn_mfma_f32_32x32x16_bf16(af[mi], bfv[ni], acc[mi][ni], 0, 0, 0); \
    } \
} while (0)

// ---------------- fused fp32 -> bf16 convert for all 5 tensors ----------------
__global__ void k_convert_all(const float* __restrict__ eeg, const float* __restrict__ mel,
                              const float* __restrict__ emb, const float* __restrict__ W2,
                              const float* __restrict__ W1,
                              unsigned short* __restrict__ o_eeg, unsigned short* __restrict__ o_mel,
                              unsigned short* __restrict__ o_emb, unsigned short* __restrict__ o_w2,
                              unsigned short* __restrict__ o_w1) {
    const int n_big = BSZ * DIM / 4;
    const int n_mid = NEMB * DIM / 4;
    const int n_w1  = DIM * DIM / 4;
    const int total = n_big * 2 + n_mid * 2 + n_w1;
    for (int i = blockIdx.x * blockDim.x + threadIdx.x; i < total; i += gridDim.x * blockDim.x) {
        const float* src; unsigned short* dst; int j = i;
        if (j < n_big) { src = eeg; dst = o_eeg; }
        else if ((j -= n_big) < n_big) { src = mel; dst = o_mel; }
        else if ((j -= n_big) < n_mid) { src = emb; dst = o_emb; }
        else if ((j -= n_mid) < n_mid) { src = W2; dst = o_w2; }
        else { j -= n_mid; src = W1; dst = o_w1; }
        float4 v = ((const float4*)src)[j];
        ushort4 o;
        o.x = f2bf(v.x); o.y = f2bf(v.y); o.z = f2bf(v.z); o.w = f2bf(v.w);
        ((ushort4*)dst)[j] = o;
    }
}

// ---------------- embedding row norms (fp32) ----------------
__global__ void k_enorm(const float* __restrict__ emb, float* __restrict__ enorm) {
    int row = blockIdx.x * 4 + (threadIdx.x >> 6);
    int lane = threadIdx.x & 63;
    const float4* p = (const float4*)(emb + row * DIM) + lane * 2;
    float4 a = p[0], b = p[1];
    float s = a.x*a.x + a.y*a.y + a.z*a.z + a.w*a.w
            + b.x*b.x + b.y*b.y + b.z*b.z + b.w*b.w;
    #pragma unroll
    for (int d = 1; d < 64; d <<= 1) s += __shfl_xor(s, d);
    if (lane == 0) enorm[row] = s;
}

// ---------------- h = LeakyReLU(eeg @ W1^T + b1), bf16 out ----------------
__launch_bounds__(256, 2)
__global__ void k_hgemm(const unsigned short* __restrict__ A,
                        const unsigned short* __restrict__ B,
                        const float* __restrict__ b1,
                        unsigned short* __restrict__ H) {
    __shared__ __align__(16) unsigned short sA[4096], sB[4096];
    int tid = threadIdx.x;
    int w = tid >> 6, lane = tid & 63;
    int wr = w >> 1, wc = w & 1;
    int lquad = lane >> 4, l15 = lane & 15;
    int mt = blockIdx.x >> 2, nt = blockIdx.x & 3;
    int m0 = mt * 128, n0 = nt * 128;

    int e0 = w * 512 + lane * 8;
    int r0 = e0 >> 5, ce = e0 & 31;
    const unsigned short* gA0 = A + (m0 + r0) * DIM + ce;
    const unsigned short* gA1 = gA0 + 64 * DIM;
    const unsigned short* gB0 = B + (n0 + r0) * DIM + ce;
    const unsigned short* gB1 = gB0 + 64 * DIM;
    unsigned short* lA0 = sA + w * 512;  unsigned short* lA1 = sA + (w + 4) * 512;
    unsigned short* lB0 = sB + w * 512;  unsigned short* lB1 = sB + (w + 4) * 512;

    int offA[4], offB[4];
    #pragma unroll
    for (int i = 0; i < 4; i++) {
        offA[i] = (wr * 64 + i * 16 + l15) * 32 + lquad * 8;
        offB[i] = (wc * 64 + i * 16 + l15) * 32 + lquad * 8;
    }

    f32x4 acc[4][4];
    #pragma unroll
    for (int mi = 0; mi < 4; mi++)
        #pragma unroll
        for (int ni = 0; ni < 4; ni++) acc[mi][ni] = 0;

    for (int kk = 0; kk < 16; kk++) {
        gl_lds16(gA0, lA0); gl_lds16(gA1, lA1);
        gl_lds16(gB0, lB0); gl_lds16(gB1, lB1);
        gA0 += 32; gA1 += 32; gB0 += 32; gB1 += 32;
        __syncthreads();
        short8 af[4], bf_[4];
        #pragma unroll
        for (int i = 0; i < 4; i++) {
            af[i]  = *(const short8*)&sA[offA[i]];
            bf_[i] = *(const short8*)&sB[offB[i]];
        }
        #pragma unroll
        for (int mi = 0; mi < 4; mi++)
            #pragma unroll
            for (int ni = 0; ni < 4; ni++)
                acc[mi][ni] = __builtin_amdgcn_mfma_f32_16x16x32_bf16(af[mi], bf_[ni], acc[mi][ni], 0, 0, 0);
        __syncthreads();
    }

    #pragma unroll
    for (int ni = 0; ni < 4; ni++) {
        int col = n0 + wc * 64 + ni * 16 + l15;
        float bv = b1[col];
        #pragma unroll
        for (int mi = 0; mi < 4; mi++) {
            int rowb = m0 + wr * 64 + mi * 16 + lquad * 4;
            #pragma unroll
            for (int rg = 0; rg < 4; rg++) {
                float v = acc[mi][ni][rg] + bv;
                v = v >= 0.f ? v : NEG * v;
                H[(rowb + rg) * DIM + col] = f2bf(v);
            }
        }
    }
}

// ---------------- GEMM 1: distances -> packed argmin per row ----------------
__launch_bounds__(256, 2)
__global__ void k_dist(const unsigned short* __restrict__ Amel,
                       const unsigned short* __restrict__ Bemb,
                       const float* __restrict__ enorm,
                       unsigned int* __restrict__ p_pmin) {
    __shared__ __align__(16) unsigned short sA[2][4096];   // 128x32 x2
    __shared__ __align__(16) unsigned short sB[2][8192];   // 256x32 x2
    __shared__ float sEn[2048];
    __shared__ unsigned int red_pm[256];
    int tid = threadIdx.x;
    int w = tid >> 6, lane = tid & 63;
    int wr2 = w >> 1, wc2 = w & 1;
    int l31 = lane & 31, hl = lane >> 5;
    int mt = blockIdx.x >> 2, split = blockIdx.x & 3;
    int m0 = mt * 128, nbase = split * (NEMB / NSPLIT);
    int wrow = wr2 * 64, wcol = wc2 * 128;

    int e0 = w * 512 + lane * 8;
    int r0 = e0 >> 5, ce = e0 & 31;
    int uW = w * 512;
    const unsigned short* gA = Amel + (m0 + r0) * DIM + ce;
    const unsigned short* gB = Bemb + (nbase + r0) * DIM + ce;

    int offA[2], offB[4];
    #pragma unroll
    for (int i = 0; i < 2; i++) offA[i] = (wrow + i * 32 + l31) * 32 + hl * 8;
    #pragma unroll
    for (int i = 0; i < 4; i++) offB[i] = (wcol + i * 32 + l31) * 32 + hl * 8;

    // stage stats tables + init reduction slots BEFORE any DMA (vmcnt hygiene)
    #pragma unroll
    for (int j = 0; j < 8; j++)
        sEn[tid + j * 256] = enorm[nbase + tid + j * 256] - 512.0f;
    red_pm[tid] = 0xFFFFFFFFu;

    ISSUE_TILE(0, 0);
    ISSUE_TILE(1, 1);

    f32x16 acc[2][4];
    #pragma unroll
    for (int mi = 0; mi < 2; mi++)
        #pragma unroll
        for (int ni = 0; ni < 4; ni++) acc[mi][ni] = 0;

    for (int g = 0; g < NG; g += 2) {
        pipe_barrier();
        COMPUTE_TILE(0);
        plain_barrier();
        ISSUE_TILE(g + 2, 0);
        pipe_barrier();
        COMPUTE_TILE(1);
        if (((g + 1) & 15) == 15) {
            int nt = (g + 1) >> 4;
            int cloc = nt * 256 + wcol + l31;
            float en[4]; unsigned int cl[4];
            #pragma unroll
            for (int ni = 0; ni < 4; ni++) {
                en[ni] = sEn[cloc + ni * 32];
                cl[ni] = (unsigned int)(nbase + cloc + ni * 32);
            }
            #pragma unroll
            for (int mi = 0; mi < 2; mi++)
                #pragma unroll
                for (int rg = 0; rg < 16; rg++) {
                    unsigned int pm = 0xFFFFFFFFu;
                    #pragma unroll
                    for (int ni = 0; ni < 4; ni++) {
                        float d = fmaf(-2.f, acc[mi][ni][rg], en[ni]);
                        unsigned int pk = (fkey(d) & 0xFFFFE000u) | cl[ni];
                        pm = pm < pk ? pm : pk;
                        acc[mi][ni][rg] = 0.f;
                    }
                    #pragma unroll
                    for (int d = 1; d < 32; d <<= 1) {
                        unsigned int o = (unsigned int)__shfl_xor((int)pm, d);
                        pm = pm < o ? pm : o;
                    }
                    if (l31 == 0) {
                        int row = wrow + mi * 32 + (rg & 3) + ((rg >> 2) << 3) + (hl << 2);
                        int slot = row * 2 + wc2;
                        unsigned int old = red_pm[slot];
                        red_pm[slot] = pm < old ? pm : old;
                    }
                }
        }
        plain_barrier();
        ISSUE_TILE(g + 3, 1);
    }

    __syncthreads();
    if (tid < 128) {
        unsigned int a = red_pm[2 * tid], b = red_pm[2 * tid + 1];
        p_pmin[split * BSZ + m0 + tid] = a < b ? a : b;
    }
}

// ---------------- GEMM 2: logits -> sum(exp) + packed argmax per row ----------------
__launch_bounds__(256, 2)
__global__ void k_logits(const unsigned short* __restrict__ Ah,
                         const unsigned short* __restrict__ Bw2,
                         const float* __restrict__ b2,
                         float* __restrict__ p_s,
                         unsigned int* __restrict__ p_pmax) {
    __shared__ __align__(16) unsigned short sA[2][4096];
    __shared__ __align__(16) unsigned short sB[2][8192];
    __shared__ float sBias[2048];
    __shared__ float red_s[256];
    __shared__ unsigned int red_pm[256];
    int tid = threadIdx.x;
    int w = tid >> 6, lane = tid & 63;
    int wr2 = w >> 1, wc2 = w & 1;
    int l31 = lane & 31, hl = lane >> 5;
    int mt = blockIdx.x >> 2, split = blockIdx.x & 3;
    int m0 = mt * 128, nbase = split * (NEMB / NSPLIT);
    int wrow = wr2 * 64, wcol = wc2 * 128;

    int e0 = w * 512 + lane * 8;
    int r0 = e0 >> 5, ce = e0 & 31;
    int uW = w * 512;
    const unsigned short* gA = Ah + (m0 + r0) * DIM + ce;
    const unsigned short* gB = Bw2 + (nbase + r0) * DIM + ce;

    int offA[2], offB[4];
    #pragma unroll
    for (int i = 0; i < 2; i++) offA[i] = (wrow + i * 32 + l31) * 32 + hl * 8;
    #pragma unroll
    for (int i = 0; i < 4; i++) offB[i] = (wcol + i * 32 + l31) * 32 + hl * 8;

    #pragma unroll
    for (int j = 0; j < 8; j++)
        sBias[tid + j * 256] = b2[nbase + tid + j * 256];
    red_s[tid] = 0.f;
    red_pm[tid] = 0u;

    ISSUE_TILE(0, 0);
    ISSUE_TILE(1, 1);

    f32x16 acc[2][4];
    #pragma unroll
    for (int mi = 0; mi < 2; mi++)
        #pragma unroll
        for (int ni = 0; ni < 4; ni++) acc[mi][ni] = 0;

    for (int g = 0; g < NG; g += 2) {
        pipe_barrier();
        COMPUTE_TILE(0);
        plain_barrier();
        ISSUE_TILE(g + 2, 0);
        pipe_barrier();
        COMPUTE_TILE(1);
        if (((g + 1) & 15) == 15) {
            int nt = (g + 1) >> 4;
            int cloc = nt * 256 + wcol + l31;
            float bb[4]; unsigned int ic[4];
            #pragma unroll
            for (int ni = 0; ni < 4; ni++) {
                bb[ni] = sBias[cloc + ni * 32];
                ic[ni] = (unsigned int)(NEMB - 1 - (nbase + cloc + ni * 32));
            }
            #pragma unroll
            for (int mi = 0; mi < 2; mi++)
                #pragma unroll
                for (int rg = 0; rg < 16; rg++) {
                    unsigned int pm = 0u;
                    float sp = 0.f;
                    #pragma unroll
                    for (int ni = 0; ni < 4; ni++) {
                        float logit = acc[mi][ni][rg] + bb[ni];
                        sp += __expf(logit);               // logits are O(1)
                        unsigned int pk = (fkey(logit) & 0xFFFFE000u) | ic[ni];
                        pm = pm > pk ? pm : pk;
                        acc[mi][ni][rg] = 0.f;
                    }
                    #pragma unroll
                    for (int d = 1; d < 32; d <<= 1) {
                        sp += __shfl_xor(sp, d);
                        unsigned int o = (unsigned int)__shfl_xor((int)pm, d);
                        pm = pm > o ? pm : o;
                    }
                    if (l31 == 0) {
                        int row = wrow + mi * 32 + (rg & 3) + ((rg >> 2) << 3) + (hl << 2);
                        int slot = row * 2 + wc2;
                        red_s[slot] += sp;
                        unsigned int old = red_pm[slot];
                        red_pm[slot] = pm > old ? pm : old;
                    }
                }
        }
        plain_barrier();
        ISSUE_TILE(g + 3, 1);
    }

    __syncthreads();
    if (tid < 128) {
        float S = red_s[2 * tid] + red_s[2 * tid + 1];
        unsigned int a = red_pm[2 * tid], b = red_pm[2 * tid + 1];
        int pidx = split * BSZ + m0 + tid;
        p_s[pidx] = S;
        p_pmax[pidx] = a > b ? a : b;
    }
}

// ---------------- merge split partials per row ----------------
__global__ void k_merge(const float* __restrict__ p_s, const unsigned int* __restrict__ p_pmax,
                        const unsigned int* __restrict__ p_pmin,
                        int* __restrict__ mel_idx, float* __restrict__ lse,
                        float* __restrict__ match) {
    int r = blockIdx.x * blockDim.x + threadIdx.x;
    if (r >= BSZ) return;
    float S = 0.f; unsigned int PM = 0u, PN = 0xFFFFFFFFu;
    #pragma unroll
    for (int sp = 0; sp < NSPLIT; sp++) {
        S += p_s[sp * BSZ + r];
        unsigned int a = p_pmax[sp * BSZ + r];
        PM = PM > a ? PM : a;
        unsigned int b = p_pmin[sp * BSZ + r];
        PN = PN < b ? PN : b;
    }
    int eidx = (NEMB - 1) - (int)(PM & 0x1FFFu);
    int midx = (int)(PN & 0x1FFFu);
    mel_idx[r] = midx;
    lse[r] = __logf(S);
    match[r] = (eidx == midx) ? 1.f : 0.f;
}

// ---------------- gather picked logit, per-row loss ----------------
__device__ __forceinline__ float dot2bf(unsigned int h, unsigned int w) {
    return bf2f((unsigned short)(h & 0xffff)) * bf2f((unsigned short)(w & 0xffff))
         + bf2f((unsigned short)(h >> 16))    * bf2f((unsigned short)(w >> 16));
}

__global__ void k_gather(const unsigned short* __restrict__ H,
                         const unsigned short* __restrict__ W2b,
                         const float* __restrict__ b2,
                         const int* __restrict__ mel_idx,
                         const float* __restrict__ lse,
                         float* __restrict__ loss) {
    int r = blockIdx.x * 4 + (threadIdx.x >> 6);
    int lane = threadIdx.x & 63;
    int idx = mel_idx[r];
    uint4 hv = *(const uint4*)(H + r * DIM + lane * 8);
    uint4 wv = *(const uint4*)(W2b + idx * DIM + lane * 8);
    float s = dot2bf(hv.x, wv.x) + dot2bf(hv.y, wv.y) + dot2bf(hv.z, wv.z) + dot2bf(hv.w, wv.w);
    #pragma unroll
    for (int d = 1; d < 64; d <<= 1) s += __shfl_xor(s, d);
    if (lane == 0) loss[r] = lse[r] - (s + b2[idx]);
}

// ---------------- final scalar reduction ----------------
__global__ void k_reduce(const float* __restrict__ loss, const float* __restrict__ match,
                         float* __restrict__ out) {
    __shared__ float sl[256], sm[256];
    int tid = threadIdx.x;
    float a = 0.f, b = 0.f;
    for (int i = tid; i < BSZ; i += 256) { a += loss[i]; b += match[i]; }
    sl[tid] = a; sm[tid] = b;
    __syncthreads();
    for (int s = 128; s > 0; s >>= 1) {
        if (tid < s) { sl[tid] += sl[tid + s]; sm[tid] += sm[tid + s]; }
        __syncthreads();
    }
    if (tid == 0) { out[0] = sl[0] / (float)BSZ; out[1] = sm[0] / (float)BSZ; }
}

extern "C" void kernel_launch(void* const* d_in, const int* in_sizes, int n_in,
                              void* d_out, int out_size, void* d_ws, size_t ws_size,
                              hipStream_t stream) {
    const float* eeg = (const float*)d_in[0];
    const float* mel = (const float*)d_in[1];
    const float* emb = (const float*)d_in[2];
    const float* W1  = (const float*)d_in[3];
    const float* b1  = (const float*)d_in[4];
    const float* W2  = (const float*)d_in[5];
    const float* b2  = (const float*)d_in[6];
    float* out = (float*)d_out;

    unsigned short* ws_mel = (unsigned short*)d_ws;
    unsigned short* ws_eeg = ws_mel + (size_t)BSZ * DIM;
    unsigned short* ws_h   = ws_eeg + (size_t)BSZ * DIM;
    unsigned short* ws_emb = ws_h   + (size_t)BSZ * DIM;
    unsigned short* ws_w2  = ws_emb + (size_t)NEMB * DIM;
    unsigned short* ws_w1  = ws_w2  + (size_t)NEMB * DIM;
    float* ws_en  = (float*)(ws_w1 + (size_t)DIM * DIM);
    float* p_s    = ws_en + NEMB;
    unsigned int* p_pmax = (unsigned int*)(p_s + (size_t)NSPLIT * BSZ);
    unsigned int* p_pmin = p_pmax + (size_t)NSPLIT * BSZ;
    int*   mel_i  = (int*)(p_pmin + (size_t)NSPLIT * BSZ);
    float* lse    = (float*)(mel_i + BSZ);
    float* match  = lse + BSZ;
    float* loss   = match + BSZ;

    k_convert_all<<<1024, 256, 0, stream>>>(eeg, mel, emb, W2, W1,
                                            ws_eeg, ws_mel, ws_emb, ws_w2, ws_w1);
    k_enorm<<<NEMB / 4, 256, 0, stream>>>(emb, ws_en);
    k_hgemm<<<(BSZ / 128) * (DIM / 128), 256, 0, stream>>>(ws_eeg, ws_w1, b1, ws_h);
    k_dist<<<(BSZ / 128) * NSPLIT, 256, 0, stream>>>(ws_mel, ws_emb, ws_en, p_pmin);
    k_logits<<<(BSZ / 128) * NSPLIT, 256, 0, stream>>>(ws_h, ws_w2, b2, p_s, p_pmax);
    k_merge<<<BSZ / 256, 256, 0, stream>>>(p_s, p_pmax, p_pmin, mel_i, lse, match);
    k_gather<<<BSZ / 4, 256, 0, stream>>>(ws_h, ws_w2, b2, mel_i, lse, loss);
    k_reduce<<<1, 256, 0, stream>>>(loss, match, out);
}

// Round 6
// 525.165 us; speedup vs baseline: 1.2205x; 1.2205x over previous
//
#include <hip/hip_runtime.h>
#include <hip/hip_bf16.h>
#include <hip/hip_fp8.h>

#define BSZ 16384
#define DIM 512
#define NEMB 8192
#define NEG 0.01f
#define NSPLIT 8
#define NG 128   // 8 nt-tiles (128 cols each) * 16 kk-steps (K=32 each)

typedef __attribute__((ext_vector_type(8))) short short8;
typedef __attribute__((ext_vector_type(4))) float f32x4;

typedef const __attribute__((address_space(1))) void GVT;
typedef __attribute__((address_space(3))) void LVT;

__device__ __forceinline__ void gl_lds16(const void* g, void* l) {
    __builtin_amdgcn_global_load_lds((GVT*)g, (LVT*)l, 16, 0, 0);
}

__device__ __forceinline__ float bf2f(unsigned short u) {
    union { unsigned int i; float f; } c; c.i = ((unsigned int)u) << 16; return c.f;
}
__device__ __forceinline__ unsigned short f2bf(float f) {
    union { __hip_bfloat16 h; unsigned short u; } c; c.h = __float2bfloat16(f); return c.u;
}
__device__ __forceinline__ unsigned char f2fp8(float f) {
    __hip_fp8_e4m3 t(f); return (unsigned char)t.__x;
}
// monotone-orderable uint key for a float
__device__ __forceinline__ unsigned int fkey(float f) {
    unsigned int u = __float_as_uint(f);
    return u ^ ((unsigned int)((int)u >> 31) | 0x80000000u);
}

// barrier leaving next tile's 2 DMA loads in flight (per-wave vmcnt)
__device__ __forceinline__ void pipe_barrier() {
    asm volatile("s_waitcnt vmcnt(2) lgkmcnt(0)\ns_barrier" ::: "memory");
}
__device__ __forceinline__ void plain_barrier() {
    asm volatile("s_barrier" ::: "memory");
}

// fp8 tile stage: A slab 128x32B, B slab 128x32B; 1 DMA each per wave.
// LDS layout: row*32 + k (bytes). Wave w covers rows [32w,32w+32);
// lane L -> row 32w + (L>>1), k-chunk (L&1)*16.
#define ISSUE8(G, BUF) do { \
    int Gm = (G) & (NG - 1); \
    int kko = (Gm & 15) << 5; \
    gl_lds16(gA8 + kko, &sA8[BUF][uW8]); \
    gl_lds16(gB8 + ((size_t)(Gm >> 4)) * (128 * DIM) + kko, &sB8[BUF][uW8]); \
} while (0)

// 16 x mfma_16x16x32_fp8_fp8 on a 64x64 wave tile; frag = 8 bytes (ds_read_b64)
#define COMPUTE8(BUF) do { \
    long af[4], bv[4]; \
    _Pragma("unroll") for (int i = 0; i < 4; i++) { \
        af[i] = *(const long*)&sA8[BUF][offA[i]]; \
        bv[i] = *(const long*)&sB8[BUF][offB[i]]; \
    } \
    _Pragma("unroll") for (int mi = 0; mi < 4; mi++) \
        _Pragma("unroll") for (int ni = 0; ni < 4; ni++) \
            acc[mi][ni] = __builtin_amdgcn_mfma_f32_16x16x32_fp8_fp8(af[mi], bv[ni], acc[mi][ni], 0, 0, 0); \
} while (0)

// ---------------- fused convert: bf16 (eeg,W1) + fp8 (mel,emb,W2) ----------------
__global__ void k_convert_all(const float* __restrict__ eeg, const float* __restrict__ mel,
                              const float* __restrict__ emb, const float* __restrict__ W2,
                              const float* __restrict__ W1,
                              unsigned short* __restrict__ o_eeg, unsigned short* __restrict__ o_w1,
                              unsigned char* __restrict__ o_mel8, unsigned char* __restrict__ o_emb8,
                              unsigned char* __restrict__ o_w28) {
    const int n_big = BSZ * DIM / 4;
    const int n_mid = NEMB * DIM / 4;
    const int n_w1  = DIM * DIM / 4;
    const int total = n_big * 2 + n_mid * 2 + n_w1;
    for (int i = blockIdx.x * blockDim.x + threadIdx.x; i < total; i += gridDim.x * blockDim.x) {
        int j = i;
        if (j < n_big) {                      // eeg -> bf16
            float4 v = ((const float4*)eeg)[j];
            ushort4 o; o.x = f2bf(v.x); o.y = f2bf(v.y); o.z = f2bf(v.z); o.w = f2bf(v.w);
            ((ushort4*)o_eeg)[j] = o;
        } else if ((j -= n_big) < n_w1) {     // W1 -> bf16
            float4 v = ((const float4*)W1)[j];
            ushort4 o; o.x = f2bf(v.x); o.y = f2bf(v.y); o.z = f2bf(v.z); o.w = f2bf(v.w);
            ((ushort4*)o_w1)[j] = o;
        } else if ((j -= n_w1) < n_big) {     // mel -> fp8
            float4 v = ((const float4*)mel)[j];
            uchar4 o; o.x = f2fp8(v.x); o.y = f2fp8(v.y); o.z = f2fp8(v.z); o.w = f2fp8(v.w);
            ((uchar4*)o_mel8)[j] = o;
        } else if ((j -= n_big) < n_mid) {    // emb -> fp8
            float4 v = ((const float4*)emb)[j];
            uchar4 o; o.x = f2fp8(v.x); o.y = f2fp8(v.y); o.z = f2fp8(v.z); o.w = f2fp8(v.w);
            ((uchar4*)o_emb8)[j] = o;
        } else {                              // W2 -> fp8
            j -= n_mid;
            float4 v = ((const float4*)W2)[j];
            uchar4 o; o.x = f2fp8(v.x); o.y = f2fp8(v.y); o.z = f2fp8(v.z); o.w = f2fp8(v.w);
            ((uchar4*)o_w28)[j] = o;
        }
    }
}

// ---------------- embedding row norms (fp32) ----------------
__global__ void k_enorm(const float* __restrict__ emb, float* __restrict__ enorm) {
    int row = blockIdx.x * 4 + (threadIdx.x >> 6);
    int lane = threadIdx.x & 63;
    const float4* p = (const float4*)(emb + row * DIM) + lane * 2;
    float4 a = p[0], b = p[1];
    float s = a.x*a.x + a.y*a.y + a.z*a.z + a.w*a.w
            + b.x*b.x + b.y*b.y + b.z*b.z + b.w*b.w;
    #pragma unroll
    for (int d = 1; d < 64; d <<= 1) s += __shfl_xor(s, d);
    if (lane == 0) enorm[row] = s;
}

// ---------------- h = LeakyReLU(eeg @ W1^T + b1): bf16 + fp8 out ----------------
__launch_bounds__(256, 2)
__global__ void k_hgemm(const unsigned short* __restrict__ A,
                        const unsigned short* __restrict__ B,
                        const float* __restrict__ b1,
                        unsigned short* __restrict__ H,
                        unsigned char* __restrict__ H8) {
    __shared__ __align__(16) unsigned short sA[4096], sB[4096];
    int tid = threadIdx.x;
    int w = tid >> 6, lane = tid & 63;
    int wr = w >> 1, wc = w & 1;
    int lquad = lane >> 4, l15 = lane & 15;
    int mt = blockIdx.x >> 2, nt = blockIdx.x & 3;
    int m0 = mt * 128, n0 = nt * 128;

    int e0 = w * 512 + lane * 8;
    int r0 = e0 >> 5, ce = e0 & 31;
    const unsigned short* gA0 = A + (m0 + r0) * DIM + ce;
    const unsigned short* gA1 = gA0 + 64 * DIM;
    const unsigned short* gB0 = B + (n0 + r0) * DIM + ce;
    const unsigned short* gB1 = gB0 + 64 * DIM;
    unsigned short* lA0 = sA + w * 512;  unsigned short* lA1 = sA + (w + 4) * 512;
    unsigned short* lB0 = sB + w * 512;  unsigned short* lB1 = sB + (w + 4) * 512;

    int offA[4], offB[4];
    #pragma unroll
    for (int i = 0; i < 4; i++) {
        offA[i] = (wr * 64 + i * 16 + l15) * 32 + lquad * 8;
        offB[i] = (wc * 64 + i * 16 + l15) * 32 + lquad * 8;
    }

    f32x4 acc[4][4];
    #pragma unroll
    for (int mi = 0; mi < 4; mi++)
        #pragma unroll
        for (int ni = 0; ni < 4; ni++) acc[mi][ni] = 0;

    for (int kk = 0; kk < 16; kk++) {
        gl_lds16(gA0, lA0); gl_lds16(gA1, lA1);
        gl_lds16(gB0, lB0); gl_lds16(gB1, lB1);
        gA0 += 32; gA1 += 32; gB0 += 32; gB1 += 32;
        __syncthreads();
        short8 af[4], bf_[4];
        #pragma unroll
        for (int i = 0; i < 4; i++) {
            af[i]  = *(const short8*)&sA[offA[i]];
            bf_[i] = *(const short8*)&sB[offB[i]];
        }
        #pragma unroll
        for (int mi = 0; mi < 4; mi++)
            #pragma unroll
            for (int ni = 0; ni < 4; ni++)
                acc[mi][ni] = __builtin_amdgcn_mfma_f32_16x16x32_bf16(af[mi], bf_[ni], acc[mi][ni], 0, 0, 0);
        __syncthreads();
    }

    #pragma unroll
    for (int ni = 0; ni < 4; ni++) {
        int col = n0 + wc * 64 + ni * 16 + l15;
        float bv = b1[col];
        #pragma unroll
        for (int mi = 0; mi < 4; mi++) {
            int rowb = m0 + wr * 64 + mi * 16 + lquad * 4;
            #pragma unroll
            for (int rg = 0; rg < 4; rg++) {
                float v = acc[mi][ni][rg] + bv;
                v = v >= 0.f ? v : NEG * v;
                H[(rowb + rg) * DIM + col] = f2bf(v);
                H8[(rowb + rg) * DIM + col] = f2fp8(v);
            }
        }
    }
}

// ---------------- GEMM 1 (fp8): distances -> packed argmin per row ----------------
__launch_bounds__(256, 2)
__global__ void k_dist(const unsigned char* __restrict__ A8,
                       const unsigned char* __restrict__ B8,
                       const float* __restrict__ enorm,
                       unsigned int* __restrict__ p_pmin) {
    __shared__ __align__(16) unsigned char sA8[2][4096], sB8[2][4096];
    __shared__ float sEn[1024];
    __shared__ unsigned int red_pm[256];
    int tid = threadIdx.x;
    int w = tid >> 6, lane = tid & 63;
    int wr = w >> 1, wc = w & 1;
    int lquad = lane >> 4, l15 = lane & 15;
    int mt = blockIdx.x >> 3, split = blockIdx.x & 7;
    int m0 = mt * 128, nbase = split * (NEMB / NSPLIT);

    int uW8 = w * 1024;  // wave-uniform LDS base (bytes)
    const unsigned char* gA8 = A8 + (size_t)(m0 + 32 * w + (lane >> 1)) * DIM + (lane & 1) * 16;
    const unsigned char* gB8 = B8 + (size_t)(nbase + 32 * w + (lane >> 1)) * DIM + (lane & 1) * 16;

    int offA[4], offB[4];
    #pragma unroll
    for (int i = 0; i < 4; i++) {
        offA[i] = (wr * 64 + i * 16 + l15) * 32 + lquad * 8;
        offB[i] = (wc * 64 + i * 16 + l15) * 32 + lquad * 8;
    }

    // stage enorm (recentred) into LDS so the epilogue never issues global loads
    #pragma unroll
    for (int j = 0; j < 4; j++)
        sEn[tid + j * 256] = enorm[nbase + tid + j * 256] - 512.0f;

    ISSUE8(0, 0);
    ISSUE8(1, 1);

    f32x4 acc[4][4];
    #pragma unroll
    for (int mi = 0; mi < 4; mi++)
        #pragma unroll
        for (int ni = 0; ni < 4; ni++) acc[mi][ni] = 0;

    unsigned int pmin[16];
    #pragma unroll
    for (int r = 0; r < 16; r++) pmin[r] = 0xFFFFFFFFu;

    for (int g = 0; g < NG; g += 2) {
        pipe_barrier();            // tile g's 2 loads done; g+1's stay in flight
        COMPUTE8(0);
        plain_barrier();
        ISSUE8(g + 2, 0);
        pipe_barrier();
        COMPUTE8(1);
        if (((g + 1) & 15) == 15) {
            int c0off = ((g + 1) >> 4) << 7;
            #pragma unroll
            for (int ni = 0; ni < 4; ni++) {
                int j = c0off + wc * 64 + ni * 16 + l15;
                float en = sEn[j];
                unsigned int cl = (unsigned int)(nbase + j);
                #pragma unroll
                for (int mi = 0; mi < 4; mi++)
                    #pragma unroll
                    for (int rg = 0; rg < 4; rg++) {
                        float d = fmaf(-2.f, acc[mi][ni][rg], en);
                        unsigned int pk = (fkey(d) & 0xFFFFE000u) | cl;
                        int r = mi * 4 + rg;
                        pmin[r] = pmin[r] < pk ? pmin[r] : pk;
                        acc[mi][ni][rg] = 0.f;
                    }
            }
        }
        plain_barrier();
        ISSUE8(g + 3, 1);
    }

    #pragma unroll
    for (int r = 0; r < 16; r++)
        #pragma unroll
        for (int d = 1; d < 16; d <<= 1) {
            unsigned int o = (unsigned int)__shfl_xor((int)pmin[r], d);
            pmin[r] = pmin[r] < o ? pmin[r] : o;
        }
    if (l15 == 0) {
        #pragma unroll
        for (int mi = 0; mi < 4; mi++)
            #pragma unroll
            for (int rg = 0; rg < 4; rg++)
                red_pm[(wr * 64 + mi * 16 + lquad * 4 + rg) * 2 + wc] = pmin[mi * 4 + rg];
    }
    __syncthreads();
    if (tid < 128) {
        unsigned int a = red_pm[2 * tid], b = red_pm[2 * tid + 1];
        p_pmin[split * BSZ + m0 + tid] = a < b ? a : b;
    }
}

// ---------------- GEMM 2 (fp8): logits -> sum(exp) + packed argmax ----------------
__launch_bounds__(256, 2)
__global__ void k_logits(const unsigned char* __restrict__ A8,
                         const unsigned char* __restrict__ B8,
                         const float* __restrict__ b2,
                         float* __restrict__ p_s,
                         unsigned int* __restrict__ p_pmax) {
    __shared__ __align__(16) unsigned char sA8[2][4096], sB8[2][4096];
    __shared__ float sBias[1024];
    __shared__ float red_s[256];
    __shared__ unsigned int red_pm[256];
    int tid = threadIdx.x;
    int w = tid >> 6, lane = tid & 63;
    int wr = w >> 1, wc = w & 1;
    int lquad = lane >> 4, l15 = lane & 15;
    int mt = blockIdx.x >> 3, split = blockIdx.x & 7;
    int m0 = mt * 128, nbase = split * (NEMB / NSPLIT);

    int uW8 = w * 1024;
    const unsigned char* gA8 = A8 + (size_t)(m0 + 32 * w + (lane >> 1)) * DIM + (lane & 1) * 16;
    const unsigned char* gB8 = B8 + (size_t)(nbase + 32 * w + (lane >> 1)) * DIM + (lane & 1) * 16;

    int offA[4], offB[4];
    #pragma unroll
    for (int i = 0; i < 4; i++) {
        offA[i] = (wr * 64 + i * 16 + l15) * 32 + lquad * 8;
        offB[i] = (wc * 64 + i * 16 + l15) * 32 + lquad * 8;
    }

    #pragma unroll
    for (int j = 0; j < 4; j++)
        sBias[tid + j * 256] = b2[nbase + tid + j * 256];

    ISSUE8(0, 0);
    ISSUE8(1, 1);

    f32x4 acc[4][4];
    #pragma unroll
    for (int mi = 0; mi < 4; mi++)
        #pragma unroll
        for (int ni = 0; ni < 4; ni++) acc[mi][ni] = 0;

    float s[16];
    unsigned int pmax[16];
    #pragma unroll
    for (int r = 0; r < 16; r++) { s[r] = 0.f; pmax[r] = 0u; }

    for (int g = 0; g < NG; g += 2) {
        pipe_barrier();
        COMPUTE8(0);
        plain_barrier();
        ISSUE8(g + 2, 0);
        pipe_barrier();
        COMPUTE8(1);
        if (((g + 1) & 15) == 15) {
            int c0off = ((g + 1) >> 4) << 7;
            #pragma unroll
            for (int ni = 0; ni < 4; ni++) {
                int j = c0off + wc * 64 + ni * 16 + l15;
                float bb = sBias[j];
                unsigned int ic = (unsigned int)(NEMB - 1 - (nbase + j));
                #pragma unroll
                for (int mi = 0; mi < 4; mi++)
                    #pragma unroll
                    for (int rg = 0; rg < 4; rg++) {
                        float logit = acc[mi][ni][rg] + bb;
                        int r = mi * 4 + rg;
                        s[r] += __expf(logit);     // logits are O(1): no max-shift needed
                        unsigned int pk = (fkey(logit) & 0xFFFFE000u) | ic;
                        pmax[r] = pmax[r] > pk ? pmax[r] : pk;
                        acc[mi][ni][rg] = 0.f;
                    }
            }
        }
        plain_barrier();
        ISSUE8(g + 3, 1);
    }

    #pragma unroll
    for (int r = 0; r < 16; r++)
        #pragma unroll
        for (int d = 1; d < 16; d <<= 1) {
            s[r] += __shfl_xor(s[r], d);
            unsigned int o = (unsigned int)__shfl_xor((int)pmax[r], d);
            pmax[r] = pmax[r] > o ? pmax[r] : o;
        }
    if (l15 == 0) {
        #pragma unroll
        for (int mi = 0; mi < 4; mi++)
            #pragma unroll
            for (int rg = 0; rg < 4; rg++) {
                int r2 = (wr * 64 + mi * 16 + lquad * 4 + rg) * 2 + wc;
                red_s[r2] = s[mi * 4 + rg];
                red_pm[r2] = pmax[mi * 4 + rg];
            }
    }
    __syncthreads();
    if (tid < 128) {
        float S = red_s[2 * tid] + red_s[2 * tid + 1];
        unsigned int a = red_pm[2 * tid], b = red_pm[2 * tid + 1];
        int pidx = split * BSZ + m0 + tid;
        p_s[pidx] = S;
        p_pmax[pidx] = a > b ? a : b;
    }
}

// ---------------- merge split partials per row ----------------
__global__ void k_merge(const float* __restrict__ p_s, const unsigned int* __restrict__ p_pmax,
                        const unsigned int* __restrict__ p_pmin,
                        int* __restrict__ mel_idx, float* __restrict__ lse,
                        float* __restrict__ match) {
    int r = blockIdx.x * blockDim.x + threadIdx.x;
    if (r >= BSZ) return;
    float S = 0.f; unsigned int PM = 0u, PN = 0xFFFFFFFFu;
    #pragma unroll
    for (int sp = 0; sp < NSPLIT; sp++) {
        S += p_s[sp * BSZ + r];
        unsigned int a = p_pmax[sp * BSZ + r];
        PM = PM > a ? PM : a;
        unsigned int b = p_pmin[sp * BSZ + r];
        PN = PN < b ? PN : b;
    }
    int eidx = (NEMB - 1) - (int)(PM & 0x1FFFu);
    int midx = (int)(PN & 0x1FFFu);
    mel_idx[r] = midx;
    lse[r] = __logf(S);
    match[r] = (eidx == midx) ? 1.f : 0.f;
}

// ---------------- gather picked logit (bf16 H x fp32 W2), per-row loss ----------------
__global__ void k_gather(const unsigned short* __restrict__ H,
                         const float* __restrict__ W2,
                         const float* __restrict__ b2,
                         const int* __restrict__ mel_idx,
                         const float* __restrict__ lse,
                         float* __restrict__ loss) {
    int r = blockIdx.x * 4 + (threadIdx.x >> 6);
    int lane = threadIdx.x & 63;
    int idx = mel_idx[r];
    uint4 hv = *(const uint4*)(H + r * DIM + lane * 8);
    const float4* wp = (const float4*)(W2 + (size_t)idx * DIM + lane * 8);
    float4 w0 = wp[0], w1 = wp[1];
    float s = bf2f((unsigned short)(hv.x & 0xffff)) * w0.x + bf2f((unsigned short)(hv.x >> 16)) * w0.y
            + bf2f((unsigned short)(hv.y & 0xffff)) * w0.z + bf2f((unsigned short)(hv.y >> 16)) * w0.w
            + bf2f((unsigned short)(hv.z & 0xffff)) * w1.x + bf2f((unsigned short)(hv.z >> 16)) * w1.y
            + bf2f((unsigned short)(hv.w & 0xffff)) * w1.z + bf2f((unsigned short)(hv.w >> 16)) * w1.w;
    #pragma unroll
    for (int d = 1; d < 64; d <<= 1) s += __shfl_xor(s, d);
    if (lane == 0) loss[r] = lse[r] - (s + b2[idx]);
}

// ---------------- final scalar reduction ----------------
__global__ void k_reduce(const float* __restrict__ loss, const float* __restrict__ match,
                         float* __restrict__ out) {
    __shared__ float sl[256], sm[256];
    int tid = threadIdx.x;
    float a = 0.f, b = 0.f;
    for (int i = tid; i < BSZ; i += 256) { a += loss[i]; b += match[i]; }
    sl[tid] = a; sm[tid] = b;
    __syncthreads();
    for (int s = 128; s > 0; s >>= 1) {
        if (tid < s) { sl[tid] += sl[tid + s]; sm[tid] += sm[tid + s]; }
        __syncthreads();
    }
    if (tid == 0) { out[0] = sl[0] / (float)BSZ; out[1] = sm[0] / (float)BSZ; }
}

extern "C" void kernel_launch(void* const* d_in, const int* in_sizes, int n_in,
                              void* d_out, int out_size, void* d_ws, size_t ws_size,
                              hipStream_t stream) {
    const float* eeg = (const float*)d_in[0];
    const float* mel = (const float*)d_in[1];
    const float* emb = (const float*)d_in[2];
    const float* W1  = (const float*)d_in[3];
    const float* b1  = (const float*)d_in[4];
    const float* W2  = (const float*)d_in[5];
    const float* b2  = (const float*)d_in[6];
    float* out = (float*)d_out;

    unsigned short* ws_eeg = (unsigned short*)d_ws;               // BSZ*DIM bf16
    unsigned short* ws_w1  = ws_eeg + (size_t)BSZ * DIM;          // DIM*DIM bf16
    unsigned short* ws_h   = ws_w1  + (size_t)DIM * DIM;          // BSZ*DIM bf16
    unsigned char*  ws_h8  = (unsigned char*)(ws_h + (size_t)BSZ * DIM);
    unsigned char*  ws_mel8 = ws_h8  + (size_t)BSZ * DIM;
    unsigned char*  ws_emb8 = ws_mel8 + (size_t)BSZ * DIM;
    unsigned char*  ws_w28  = ws_emb8 + (size_t)NEMB * DIM;
    float* ws_en  = (float*)(ws_w28 + (size_t)NEMB * DIM);
    float* p_s    = ws_en + NEMB;
    unsigned int* p_pmax = (unsigned int*)(p_s + (size_t)NSPLIT * BSZ);
    unsigned int* p_pmin = p_pmax + (size_t)NSPLIT * BSZ;
    int*   mel_i  = (int*)(p_pmin + (size_t)NSPLIT * BSZ);
    float* lse    = (float*)(mel_i + BSZ);
    float* match  = lse + BSZ;
    float* loss   = match + BSZ;

    k_convert_all<<<1024, 256, 0, stream>>>(eeg, mel, emb, W2, W1,
                                            ws_eeg, ws_w1, ws_mel8, ws_emb8, ws_w28);
    k_enorm<<<NEMB / 4, 256, 0, stream>>>(emb, ws_en);
    k_hgemm<<<(BSZ / 128) * (DIM / 128), 256, 0, stream>>>(ws_eeg, ws_w1, b1, ws_h, ws_h8);
    k_dist<<<(BSZ / 128) * NSPLIT, 256, 0, stream>>>(ws_mel8, ws_emb8, ws_en, p_pmin);
    k_logits<<<(BSZ / 128) * NSPLIT, 256, 0, stream>>>(ws_h8, ws_w28, b2, p_s, p_pmax);
    k_merge<<<BSZ / 256, 256, 0, stream>>>(p_s, p_pmax, p_pmin, mel_i, lse, match);
    k_gather<<<BSZ / 4, 256, 0, stream>>>(ws_h, W2, b2, mel_i, lse, loss);
    k_reduce<<<1, 256, 0, stream>>>(loss, match, out);
}

// Round 7
// 429.396 us; speedup vs baseline: 1.4927x; 1.2230x over previous
//
#include <hip/hip_runtime.h>
#include <hip/hip_bf16.h>
#include <hip/hip_fp8.h>

#define BSZ 16384
#define DIM 512
#define NEMB 8192
#define NEG 0.01f
#define NSPLIT 8
#define NG 64   // 8 nt-tiles (128 cols each) * 8 kg-steps (K=64 each)

typedef __attribute__((ext_vector_type(8))) short short8;
typedef __attribute__((ext_vector_type(4))) float f32x4;
typedef __attribute__((ext_vector_type(2))) long long2v;

typedef const __attribute__((address_space(1))) void GVT;
typedef __attribute__((address_space(3))) void LVT;

__device__ __forceinline__ void gl_lds16(const void* g, void* l) {
    __builtin_amdgcn_global_load_lds((GVT*)g, (LVT*)l, 16, 0, 0);
}

__device__ __forceinline__ float bf2f(unsigned short u) {
    union { unsigned int i; float f; } c; c.i = ((unsigned int)u) << 16; return c.f;
}
__device__ __forceinline__ unsigned short f2bf(float f) {
    union { __hip_bfloat16 h; unsigned short u; } c; c.h = __float2bfloat16(f); return c.u;
}
__device__ __forceinline__ unsigned char f2fp8(float f) {
    __hip_fp8_e4m3 t(f); return (unsigned char)t.__x;
}
// monotone-orderable uint key for a float
__device__ __forceinline__ unsigned int fkey(float f) {
    unsigned int u = __float_as_uint(f);
    return u ^ ((unsigned int)((int)u >> 31) | 0x80000000u);
}

// packed fragment address for element (r, k) of an [R x 512] fp8 matrix.
// fragment block = 16 rows x 64 k-bytes = 64 lanes x 16B; lane L = lquad*16 + (r&15)
// holds [k=lquad*8..+8 | k=32+lquad*8..+8] of its row.
__device__ __forceinline__ size_t pack_addr(int r, int k) {
    int kg = k >> 6, ko = k & 63;
    int half = ko >> 5, lq = (ko & 31) >> 3, sub = ko & 7;
    int L = lq * 16 + (r & 15);
    return ((size_t)((r >> 4) * 8 + kg) << 10) + (size_t)(L << 4) + (half << 3) + sub;
}

// barrier leaving next tile's 4 DMA loads in flight (per-wave vmcnt)
__device__ __forceinline__ void pipe_barrier() {
    asm volatile("s_waitcnt vmcnt(4) lgkmcnt(0)\ns_barrier" ::: "memory");
}
__device__ __forceinline__ void plain_barrier() {
    asm volatile("s_barrier" ::: "memory");
}

// one K=64 tile: A 128x64B packed = 8KB (2 DMA/wave), B 128x64B = 8KB (2 DMA/wave)
#define ISSUE8(G, BUF) do { \
    int Gm = (G) & (NG - 1); \
    size_t off = (size_t)((Gm & 7) << 10); \
    size_t bo  = off + ((size_t)(Gm >> 3) << 16); \
    gl_lds16(gA8 + off,         &sA8[BUF][uWd]); \
    gl_lds16(gA8 + off + 32768, &sA8[BUF][uWd + 4096]); \
    gl_lds16(gB8 + bo,          &sB8[BUF][uWd]); \
    gl_lds16(gB8 + bo + 32768,  &sB8[BUF][uWd + 4096]); \
} while (0)

// 32 x mfma_16x16x32_fp8_fp8 per wave on a 64x64 tile, K=64: 8 ds_read_b128 total
#define COMPUTE8(BUF) do { \
    long2v fa[4], fb[4]; \
    _Pragma("unroll") for (int i = 0; i < 4; i++) { \
        fa[i] = *(const long2v*)&sA8[BUF][offA[i]]; \
        fb[i] = *(const long2v*)&sB8[BUF][offB[i]]; \
    } \
    _Pragma("unroll") for (int kk = 0; kk < 2; kk++) \
        _Pragma("unroll") for (int mi = 0; mi < 4; mi++) \
            _Pragma("unroll") for (int ni = 0; ni < 4; ni++) \
                acc[mi][ni] = __builtin_amdgcn_mfma_f32_16x16x32_fp8_fp8(fa[mi][kk], fb[ni][kk], acc[mi][ni], 0, 0, 0); \
} while (0)

// ---------------- fused convert: bf16 (eeg,W1) + packed fp8 (mel,emb,W2) ----------------
__global__ void k_convert_all(const float* __restrict__ eeg, const float* __restrict__ mel,
                              const float* __restrict__ emb, const float* __restrict__ W2,
                              const float* __restrict__ W1,
                              unsigned short* __restrict__ o_eeg, unsigned short* __restrict__ o_w1,
                              unsigned char* __restrict__ o_mel8, unsigned char* __restrict__ o_emb8,
                              unsigned char* __restrict__ o_w28) {
    const int n_big = BSZ * DIM / 4;
    const int n_mid = NEMB * DIM / 4;
    const int n_w1  = DIM * DIM / 4;
    const int total = n_big * 2 + n_mid * 2 + n_w1;
    for (int i = blockIdx.x * blockDim.x + threadIdx.x; i < total; i += gridDim.x * blockDim.x) {
        int j = i;
        if (j < n_big) {                      // eeg -> bf16 linear
            float4 v = ((const float4*)eeg)[j];
            ushort4 o; o.x = f2bf(v.x); o.y = f2bf(v.y); o.z = f2bf(v.z); o.w = f2bf(v.w);
            ((ushort4*)o_eeg)[j] = o;
        } else if ((j -= n_big) < n_w1) {     // W1 -> bf16 linear
            float4 v = ((const float4*)W1)[j];
            ushort4 o; o.x = f2bf(v.x); o.y = f2bf(v.y); o.z = f2bf(v.z); o.w = f2bf(v.w);
            ((ushort4*)o_w1)[j] = o;
        } else if ((j -= n_w1) < n_big) {     // mel -> fp8 packed
            float4 v = ((const float4*)mel)[j];
            uchar4 o; o.x = f2fp8(v.x); o.y = f2fp8(v.y); o.z = f2fp8(v.z); o.w = f2fp8(v.w);
            *(uchar4*)(o_mel8 + pack_addr(j >> 7, (j & 127) * 4)) = o;
        } else if ((j -= n_big) < n_mid) {    // emb -> fp8 packed
            float4 v = ((const float4*)emb)[j];
            uchar4 o; o.x = f2fp8(v.x); o.y = f2fp8(v.y); o.z = f2fp8(v.z); o.w = f2fp8(v.w);
            *(uchar4*)(o_emb8 + pack_addr(j >> 7, (j & 127) * 4)) = o;
        } else {                              // W2 -> fp8 packed
            j -= n_mid;
            float4 v = ((const float4*)W2)[j];
            uchar4 o; o.x = f2fp8(v.x); o.y = f2fp8(v.y); o.z = f2fp8(v.z); o.w = f2fp8(v.w);
            *(uchar4*)(o_w28 + pack_addr(j >> 7, (j & 127) * 4)) = o;
        }
    }
}

// ---------------- embedding row norms (fp32) ----------------
__global__ void k_enorm(const float* __restrict__ emb, float* __restrict__ enorm) {
    int row = blockIdx.x * 4 + (threadIdx.x >> 6);
    int lane = threadIdx.x & 63;
    const float4* p = (const float4*)(emb + row * DIM) + lane * 2;
    float4 a = p[0], b = p[1];
    float s = a.x*a.x + a.y*a.y + a.z*a.z + a.w*a.w
            + b.x*b.x + b.y*b.y + b.z*b.z + b.w*b.w;
    #pragma unroll
    for (int d = 1; d < 64; d <<= 1) s += __shfl_xor(s, d);
    if (lane == 0) enorm[row] = s;
}

// ---------------- h = LeakyReLU(eeg @ W1^T + b1): bf16 + packed fp8 out ----------------
__launch_bounds__(256, 2)
__global__ void k_hgemm(const unsigned short* __restrict__ A,
                        const unsigned short* __restrict__ B,
                        const float* __restrict__ b1,
                        unsigned short* __restrict__ H,
                        unsigned char* __restrict__ H8) {
    __shared__ __align__(16) unsigned short sA[4096], sB[4096];
    int tid = threadIdx.x;
    int w = tid >> 6, lane = tid & 63;
    int wr = w >> 1, wc = w & 1;
    int lquad = lane >> 4, l15 = lane & 15;
    int mt = blockIdx.x >> 2, nt = blockIdx.x & 3;
    int m0 = mt * 128, n0 = nt * 128;

    int e0 = w * 512 + lane * 8;
    int r0 = e0 >> 5, ce = e0 & 31;
    const unsigned short* gA0 = A + (m0 + r0) * DIM + ce;
    const unsigned short* gA1 = gA0 + 64 * DIM;
    const unsigned short* gB0 = B + (n0 + r0) * DIM + ce;
    const unsigned short* gB1 = gB0 + 64 * DIM;
    unsigned short* lA0 = sA + w * 512;  unsigned short* lA1 = sA + (w + 4) * 512;
    unsigned short* lB0 = sB + w * 512;  unsigned short* lB1 = sB + (w + 4) * 512;

    int offA[4], offB[4];
    #pragma unroll
    for (int i = 0; i < 4; i++) {
        offA[i] = (wr * 64 + i * 16 + l15) * 32 + lquad * 8;
        offB[i] = (wc * 64 + i * 16 + l15) * 32 + lquad * 8;
    }

    f32x4 acc[4][4];
    #pragma unroll
    for (int mi = 0; mi < 4; mi++)
        #pragma unroll
        for (int ni = 0; ni < 4; ni++) acc[mi][ni] = 0;

    for (int kk = 0; kk < 16; kk++) {
        gl_lds16(gA0, lA0); gl_lds16(gA1, lA1);
        gl_lds16(gB0, lB0); gl_lds16(gB1, lB1);
        gA0 += 32; gA1 += 32; gB0 += 32; gB1 += 32;
        __syncthreads();
        short8 af[4], bf_[4];
        #pragma unroll
        for (int i = 0; i < 4; i++) {
            af[i]  = *(const short8*)&sA[offA[i]];
            bf_[i] = *(const short8*)&sB[offB[i]];
        }
        #pragma unroll
        for (int mi = 0; mi < 4; mi++)
            #pragma unroll
            for (int ni = 0; ni < 4; ni++)
                acc[mi][ni] = __builtin_amdgcn_mfma_f32_16x16x32_bf16(af[mi], bf_[ni], acc[mi][ni], 0, 0, 0);
        __syncthreads();
    }

    #pragma unroll
    for (int ni = 0; ni < 4; ni++) {
        int col = n0 + wc * 64 + ni * 16 + l15;
        float bv = b1[col];
        #pragma unroll
        for (int mi = 0; mi < 4; mi++) {
            int rowb = m0 + wr * 64 + mi * 16 + lquad * 4;
            #pragma unroll
            for (int rg = 0; rg < 4; rg++) {
                float v = acc[mi][ni][rg] + bv;
                v = v >= 0.f ? v : NEG * v;
                H[(rowb + rg) * DIM + col] = f2bf(v);
                H8[pack_addr(rowb + rg, col)] = f2fp8(v);
            }
        }
    }
}

// ---------------- GEMM 1 (packed fp8): distances -> packed argmin per row ----------------
__launch_bounds__(256, 2)
__global__ void k_dist(const unsigned char* __restrict__ A8,
                       const unsigned char* __restrict__ B8,
                       const float* __restrict__ enorm,
                       unsigned int* __restrict__ p_pmin) {
    __shared__ __align__(16) unsigned char sA8[2][8192], sB8[2][8192];
    __shared__ float sEn[1024];
    __shared__ unsigned int red_pm[256];
    int tid = threadIdx.x;
    int w = tid >> 6, lane = tid & 63;
    int wr = w >> 1, wc = w & 1;
    int lquad = lane >> 4, l15 = lane & 15;
    int mt = blockIdx.x >> 3, split = blockIdx.x & 7;
    int m0 = mt * 128, nbase = split * (NEMB / NSPLIT);

    int uWd = w * 1024;  // wave-uniform LDS dst base (bytes)
    const unsigned char* gA8 = A8 + (size_t)(m0 + 16 * w) * 512 + lane * 16;
    const unsigned char* gB8 = B8 + (size_t)(nbase + 16 * w) * 512 + lane * 16;

    int offA[4], offB[4];
    #pragma unroll
    for (int i = 0; i < 4; i++) {
        offA[i] = (wr * 4 + i) * 1024 + lane * 16;
        offB[i] = (wc * 4 + i) * 1024 + lane * 16;
    }

    // stage enorm (recentred) into LDS so the epilogue never issues global loads
    #pragma unroll
    for (int j = 0; j < 4; j++)
        sEn[tid + j * 256] = enorm[nbase + tid + j * 256] - 512.0f;

    ISSUE8(0, 0);
    ISSUE8(1, 1);

    f32x4 acc[4][4];
    #pragma unroll
    for (int mi = 0; mi < 4; mi++)
        #pragma unroll
        for (int ni = 0; ni < 4; ni++) acc[mi][ni] = 0;

    unsigned int pmin[16];
    #pragma unroll
    for (int r = 0; r < 16; r++) pmin[r] = 0xFFFFFFFFu;

    for (int g = 0; g < NG; g += 2) {
        pipe_barrier();            // tile g's 4 loads done; g+1's stay in flight
        COMPUTE8(0);
        plain_barrier();
        ISSUE8(g + 2, 0);
        pipe_barrier();
        COMPUTE8(1);
        if (((g + 1) & 7) == 7) {
            int c0off = ((g + 1) >> 3) << 7;
            #pragma unroll
            for (int ni = 0; ni < 4; ni++) {
                int j = c0off + wc * 64 + ni * 16 + l15;
                float en = sEn[j];
                unsigned int cl = (unsigned int)(nbase + j);
                #pragma unroll
                for (int mi = 0; mi < 4; mi++)
                    #pragma unroll
                    for (int rg = 0; rg < 4; rg++) {
                        float d = fmaf(-2.f, acc[mi][ni][rg], en);
                        unsigned int pk = (fkey(d) & 0xFFFFE000u) | cl;
                        int r = mi * 4 + rg;
                        pmin[r] = pmin[r] < pk ? pmin[r] : pk;
                        acc[mi][ni][rg] = 0.f;
                    }
            }
        }
        plain_barrier();
        ISSUE8(g + 3, 1);
    }

    #pragma unroll
    for (int r = 0; r < 16; r++)
        #pragma unroll
        for (int d = 1; d < 16; d <<= 1) {
            unsigned int o = (unsigned int)__shfl_xor((int)pmin[r], d);
            pmin[r] = pmin[r] < o ? pmin[r] : o;
        }
    if (l15 == 0) {
        #pragma unroll
        for (int mi = 0; mi < 4; mi++)
            #pragma unroll
            for (int rg = 0; rg < 4; rg++)
                red_pm[(wr * 64 + mi * 16 + lquad * 4 + rg) * 2 + wc] = pmin[mi * 4 + rg];
    }
    __syncthreads();
    if (tid < 128) {
        unsigned int a = red_pm[2 * tid], b = red_pm[2 * tid + 1];
        p_pmin[split * BSZ + m0 + tid] = a < b ? a : b;
    }
}

// ---------------- GEMM 2 (packed fp8): logits -> sum(exp) + packed argmax ----------------
__launch_bounds__(256, 2)
__global__ void k_logits(const unsigned char* __restrict__ A8,
                         const unsigned char* __restrict__ B8,
                         const float* __restrict__ b2,
                         float* __restrict__ p_s,
                         unsigned int* __restrict__ p_pmax) {
    __shared__ __align__(16) unsigned char sA8[2][8192], sB8[2][8192];
    __shared__ float sBias[1024];
    __shared__ float red_s[256];
    __shared__ unsigned int red_pm[256];
    int tid = threadIdx.x;
    int w = tid >> 6, lane = tid & 63;
    int wr = w >> 1, wc = w & 1;
    int lquad = lane >> 4, l15 = lane & 15;
    int mt = blockIdx.x >> 3, split = blockIdx.x & 7;
    int m0 = mt * 128, nbase = split * (NEMB / NSPLIT);

    int uWd = w * 1024;
    const unsigned char* gA8 = A8 + (size_t)(m0 + 16 * w) * 512 + lane * 16;
    const unsigned char* gB8 = B8 + (size_t)(nbase + 16 * w) * 512 + lane * 16;

    int offA[4], offB[4];
    #pragma unroll
    for (int i = 0; i < 4; i++) {
        offA[i] = (wr * 4 + i) * 1024 + lane * 16;
        offB[i] = (wc * 4 + i) * 1024 + lane * 16;
    }

    #pragma unroll
    for (int j = 0; j < 4; j++)
        sBias[tid + j * 256] = b2[nbase + tid + j * 256];

    ISSUE8(0, 0);
    ISSUE8(1, 1);

    f32x4 acc[4][4];
    #pragma unroll
    for (int mi = 0; mi < 4; mi++)
        #pragma unroll
        for (int ni = 0; ni < 4; ni++) acc[mi][ni] = 0;

    float s[16];
    unsigned int pmax[16];
    #pragma unroll
    for (int r = 0; r < 16; r++) { s[r] = 0.f; pmax[r] = 0u; }

    for (int g = 0; g < NG; g += 2) {
        pipe_barrier();
        COMPUTE8(0);
        plain_barrier();
        ISSUE8(g + 2, 0);
        pipe_barrier();
        COMPUTE8(1);
        if (((g + 1) & 7) == 7) {
            int c0off = ((g + 1) >> 3) << 7;
            #pragma unroll
            for (int ni = 0; ni < 4; ni++) {
                int j = c0off + wc * 64 + ni * 16 + l15;
                float bb = sBias[j];
                unsigned int ic = (unsigned int)(NEMB - 1 - (nbase + j));
                #pragma unroll
                for (int mi = 0; mi < 4; mi++)
                    #pragma unroll
                    for (int rg = 0; rg < 4; rg++) {
                        float logit = acc[mi][ni][rg] + bb;
                        int r = mi * 4 + rg;
                        s[r] += __expf(logit);     // logits are O(1): no max-shift needed
                        unsigned int pk = (fkey(logit) & 0xFFFFE000u) | ic;
                        pmax[r] = pmax[r] > pk ? pmax[r] : pk;
                        acc[mi][ni][rg] = 0.f;
                    }
            }
        }
        plain_barrier();
        ISSUE8(g + 3, 1);
    }

    #pragma unroll
    for (int r = 0; r < 16; r++)
        #pragma unroll
        for (int d = 1; d < 16; d <<= 1) {
            s[r] += __shfl_xor(s[r], d);
            unsigned int o = (unsigned int)__shfl_xor((int)pmax[r], d);
            pmax[r] = pmax[r] > o ? pmax[r] : o;
        }
    if (l15 == 0) {
        #pragma unroll
        for (int mi = 0; mi < 4; mi++)
            #pragma unroll
            for (int rg = 0; rg < 4; rg++) {
                int r2 = (wr * 64 + mi * 16 + lquad * 4 + rg) * 2 + wc;
                red_s[r2] = s[mi * 4 + rg];
                red_pm[r2] = pmax[mi * 4 + rg];
            }
    }
    __syncthreads();
    if (tid < 128) {
        float S = red_s[2 * tid] + red_s[2 * tid + 1];
        unsigned int a = red_pm[2 * tid], b = red_pm[2 * tid + 1];
        int pidx = split * BSZ + m0 + tid;
        p_s[pidx] = S;
        p_pmax[pidx] = a > b ? a : b;
    }
}

// ---------------- merge split partials per row ----------------
__global__ void k_merge(const float* __restrict__ p_s, const unsigned int* __restrict__ p_pmax,
                        const unsigned int* __restrict__ p_pmin,
                        int* __restrict__ mel_idx, float* __restrict__ lse,
                        float* __restrict__ match) {
    int r = blockIdx.x * blockDim.x + threadIdx.x;
    if (r >= BSZ) return;
    float S = 0.f; unsigned int PM = 0u, PN = 0xFFFFFFFFu;
    #pragma unroll
    for (int sp = 0; sp < NSPLIT; sp++) {
        S += p_s[sp * BSZ + r];
        unsigned int a = p_pmax[sp * BSZ + r];
        PM = PM > a ? PM : a;
        unsigned int b = p_pmin[sp * BSZ + r];
        PN = PN < b ? PN : b;
    }
    int eidx = (NEMB - 1) - (int)(PM & 0x1FFFu);
    int midx = (int)(PN & 0x1FFFu);
    mel_idx[r] = midx;
    lse[r] = __logf(S);
    match[r] = (eidx == midx) ? 1.f : 0.f;
}

// ---------------- gather picked logit (bf16 H x fp32 W2), per-row loss ----------------
__global__ void k_gather(const unsigned short* __restrict__ H,
                         const float* __restrict__ W2,
                         const float* __restrict__ b2,
                         const int* __restrict__ mel_idx,
                         const float* __restrict__ lse,
                         float* __restrict__ loss) {
    int r = blockIdx.x * 4 + (threadIdx.x >> 6);
    int lane = threadIdx.x & 63;
    int idx = mel_idx[r];
    uint4 hv = *(const uint4*)(H + r * DIM + lane * 8);
    const float4* wp = (const float4*)(W2 + (size_t)idx * DIM + lane * 8);
    float4 w0 = wp[0], w1 = wp[1];
    float s = bf2f((unsigned short)(hv.x & 0xffff)) * w0.x + bf2f((unsigned short)(hv.x >> 16)) * w0.y
            + bf2f((unsigned short)(hv.y & 0xffff)) * w0.z + bf2f((unsigned short)(hv.y >> 16)) * w0.w
            + bf2f((unsigned short)(hv.z & 0xffff)) * w1.x + bf2f((unsigned short)(hv.z >> 16)) * w1.y
            + bf2f((unsigned short)(hv.w & 0xffff)) * w1.z + bf2f((unsigned short)(hv.w >> 16)) * w1.w;
    #pragma unroll
    for (int d = 1; d < 64; d <<= 1) s += __shfl_xor(s, d);
    if (lane == 0) loss[r] = lse[r] - (s + b2[idx]);
}

// ---------------- final scalar reduction ----------------
__global__ void k_reduce(const float* __restrict__ loss, const float* __restrict__ match,
                         float* __restrict__ out) {
    __shared__ float sl[256], sm[256];
    int tid = threadIdx.x;
    float a = 0.f, b = 0.f;
    for (int i = tid; i < BSZ; i += 256) { a += loss[i]; b += match[i]; }
    sl[tid] = a; sm[tid] = b;
    __syncthreads();
    for (int s = 128; s > 0; s >>= 1) {
        if (tid < s) { sl[tid] += sl[tid + s]; sm[tid] += sm[tid + s]; }
        __syncthreads();
    }
    if (tid == 0) { out[0] = sl[0] / (float)BSZ; out[1] = sm[0] / (float)BSZ; }
}

extern "C" void kernel_launch(void* const* d_in, const int* in_sizes, int n_in,
                              void* d_out, int out_size, void* d_ws, size_t ws_size,
                              hipStream_t stream) {
    const float* eeg = (const float*)d_in[0];
    const float* mel = (const float*)d_in[1];
    const float* emb = (const float*)d_in[2];
    const float* W1  = (const float*)d_in[3];
    const float* b1  = (const float*)d_in[4];
    const float* W2  = (const float*)d_in[5];
    const float* b2  = (const float*)d_in[6];
    float* out = (float*)d_out;

    unsigned short* ws_eeg = (unsigned short*)d_ws;               // BSZ*DIM bf16
    unsigned short* ws_w1  = ws_eeg + (size_t)BSZ * DIM;          // DIM*DIM bf16
    unsigned short* ws_h   = ws_w1  + (size_t)DIM * DIM;          // BSZ*DIM bf16
    unsigned char*  ws_h8  = (unsigned char*)(ws_h + (size_t)BSZ * DIM);
    unsigned char*  ws_mel8 = ws_h8  + (size_t)BSZ * DIM;
    unsigned char*  ws_emb8 = ws_mel8 + (size_t)BSZ * DIM;
    unsigned char*  ws_w28  = ws_emb8 + (size_t)NEMB * DIM;
    float* ws_en  = (float*)(ws_w28 + (size_t)NEMB * DIM);
    float* p_s    = ws_en + NEMB;
    unsigned int* p_pmax = (unsigned int*)(p_s + (size_t)NSPLIT * BSZ);
    unsigned int* p_pmin = p_pmax + (size_t)NSPLIT * BSZ;
    int*   mel_i  = (int*)(p_pmin + (size_t)NSPLIT * BSZ);
    float* lse    = (float*)(mel_i + BSZ);
    float* match  = lse + BSZ;
    float* loss   = match + BSZ;

    k_convert_all<<<1024, 256, 0, stream>>>(eeg, mel, emb, W2, W1,
                                            ws_eeg, ws_w1, ws_mel8, ws_emb8, ws_w28);
    k_enorm<<<NEMB / 4, 256, 0, stream>>>(emb, ws_en);
    k_hgemm<<<(BSZ / 128) * (DIM / 128), 256, 0, stream>>>(ws_eeg, ws_w1, b1, ws_h, ws_h8);
    k_dist<<<(BSZ / 128) * NSPLIT, 256, 0, stream>>>(ws_mel8, ws_emb8, ws_en, p_pmin);
    k_logits<<<(BSZ / 128) * NSPLIT, 256, 0, stream>>>(ws_h8, ws_w28, b2, p_s, p_pmax);
    k_merge<<<BSZ / 256, 256, 0, stream>>>(p_s, p_pmax, p_pmin, mel_i, lse, match);
    k_gather<<<BSZ / 4, 256, 0, stream>>>(ws_h, W2, b2, mel_i, lse, loss);
    k_reduce<<<1, 256, 0, stream>>>(loss, match, out);
}

// Round 8
// 402.128 us; speedup vs baseline: 1.5940x; 1.0678x over previous
//
#include <hip/hip_runtime.h>
#include <hip/hip_bf16.h>
#include <hip/hip_fp8.h>

#define BSZ 16384
#define DIM 512
#define NEMB 8192
#define NEG 0.01f
#define NSPLIT 8
#define NG 64   // 8 nt-tiles (128 cols each) * 8 kg-steps (K=64 each)

typedef __attribute__((ext_vector_type(8))) short short8;
typedef __attribute__((ext_vector_type(4))) float f32x4;
typedef __attribute__((ext_vector_type(2))) long long2v;

typedef const __attribute__((address_space(1))) void GVT;
typedef __attribute__((address_space(3))) void LVT;

__device__ __forceinline__ void gl_lds16(const void* g, void* l) {
    __builtin_amdgcn_global_load_lds((GVT*)g, (LVT*)l, 16, 0, 0);
}

__device__ __forceinline__ float bf2f(unsigned short u) {
    union { unsigned int i; float f; } c; c.i = ((unsigned int)u) << 16; return c.f;
}
__device__ __forceinline__ unsigned short f2bf(float f) {
    union { __hip_bfloat16 h; unsigned short u; } c; c.h = __float2bfloat16(f); return c.u;
}
__device__ __forceinline__ unsigned char f2fp8(float f) {
    __hip_fp8_e4m3 t(f); return (unsigned char)t.__x;
}
// monotone-orderable uint key for a float
__device__ __forceinline__ unsigned int fkey(float f) {
    unsigned int u = __float_as_uint(f);
    return u ^ ((unsigned int)((int)u >> 31) | 0x80000000u);
}

// packed fragment address for element (r, k) of an [R x 512] fp8 matrix.
// fragment block = 16 rows x 64 k-bytes = 64 lanes x 16B; lane L = lquad*16 + (r&15)
// holds [k=lquad*8..+8 | k=32+lquad*8..+8] of its row.
__device__ __forceinline__ size_t pack_addr(int r, int k) {
    int kg = k >> 6, ko = k & 63;
    int half = ko >> 5, lq = (ko & 31) >> 3, sub = ko & 7;
    int L = lq * 16 + (r & 15);
    return ((size_t)((r >> 4) * 8 + kg) << 10) + (size_t)(L << 4) + (half << 3) + sub;
}

// barrier leaving next tile's 4 DMA loads in flight (per-wave vmcnt)
__device__ __forceinline__ void pipe_barrier() {
    asm volatile("s_waitcnt vmcnt(4) lgkmcnt(0)\ns_barrier" ::: "memory");
}
__device__ __forceinline__ void plain_barrier() {
    asm volatile("s_barrier" ::: "memory");
}

// one K=64 tile: A 128x64B packed = 8KB (2 DMA/wave), B 128x64B = 8KB (2 DMA/wave)
#define ISSUE8(G, BUF) do { \
    int Gm = (G) & (NG - 1); \
    size_t off = (size_t)((Gm & 7) << 10); \
    size_t bo  = off + ((size_t)(Gm >> 3) << 16); \
    gl_lds16(gA8 + off,         &sA8[BUF][uWd]); \
    gl_lds16(gA8 + off + 32768, &sA8[BUF][uWd + 4096]); \
    gl_lds16(gB8 + bo,          &sB8[BUF][uWd]); \
    gl_lds16(gB8 + bo + 32768,  &sB8[BUF][uWd + 4096]); \
} while (0)

// 32 x mfma_16x16x32_fp8_fp8 per wave on a 64x64 tile, K=64: 8 ds_read_b128 total
#define COMPUTE8(BUF) do { \
    long2v fa[4], fb[4]; \
    _Pragma("unroll") for (int i = 0; i < 4; i++) { \
        fa[i] = *(const long2v*)&sA8[BUF][offA[i]]; \
        fb[i] = *(const long2v*)&sB8[BUF][offB[i]]; \
    } \
    _Pragma("unroll") for (int kk = 0; kk < 2; kk++) \
        _Pragma("unroll") for (int mi = 0; mi < 4; mi++) \
            _Pragma("unroll") for (int ni = 0; ni < 4; ni++) \
                acc[mi][ni] = __builtin_amdgcn_mfma_f32_16x16x32_fp8_fp8(fa[mi][kk], fb[ni][kk], acc[mi][ni], 0, 0, 0); \
} while (0)

// ---------------- prep: converts + enorm + zero accumulators ----------------
__global__ void k_prep(const float* __restrict__ eeg, const float* __restrict__ mel,
                       const float* __restrict__ emb, const float* __restrict__ W2,
                       const float* __restrict__ W1,
                       unsigned short* __restrict__ o_eeg, unsigned short* __restrict__ o_w1,
                       unsigned char* __restrict__ o_mel8, unsigned char* __restrict__ o_emb8,
                       unsigned char* __restrict__ o_w28,
                       float* __restrict__ enorm,
                       float* __restrict__ acc2, int* __restrict__ cnt) {
    int bid = blockIdx.x, tid = threadIdx.x;
    if (bid == 0 && tid == 0) { acc2[0] = 0.f; acc2[1] = 0.f; *cnt = 0; }
    if (bid < 1024) {
        const int n_big = BSZ * DIM / 4;
        const int n_mid = NEMB * DIM / 4;
        const int n_w1  = DIM * DIM / 4;
        const int total = n_big * 2 + n_mid * 2 + n_w1;
        for (int i = bid * 256 + tid; i < total; i += 1024 * 256) {
            int j = i;
            if (j < n_big) {                      // eeg -> bf16 linear
                float4 v = ((const float4*)eeg)[j];
                ushort4 o; o.x = f2bf(v.x); o.y = f2bf(v.y); o.z = f2bf(v.z); o.w = f2bf(v.w);
                ((ushort4*)o_eeg)[j] = o;
            } else if ((j -= n_big) < n_w1) {     // W1 -> bf16 linear
                float4 v = ((const float4*)W1)[j];
                ushort4 o; o.x = f2bf(v.x); o.y = f2bf(v.y); o.z = f2bf(v.z); o.w = f2bf(v.w);
                ((ushort4*)o_w1)[j] = o;
            } else if ((j -= n_w1) < n_big) {     // mel -> fp8 packed
                float4 v = ((const float4*)mel)[j];
                uchar4 o; o.x = f2fp8(v.x); o.y = f2fp8(v.y); o.z = f2fp8(v.z); o.w = f2fp8(v.w);
                *(uchar4*)(o_mel8 + pack_addr(j >> 7, (j & 127) * 4)) = o;
            } else if ((j -= n_big) < n_mid) {    // emb -> fp8 packed
                float4 v = ((const float4*)emb)[j];
                uchar4 o; o.x = f2fp8(v.x); o.y = f2fp8(v.y); o.z = f2fp8(v.z); o.w = f2fp8(v.w);
                *(uchar4*)(o_emb8 + pack_addr(j >> 7, (j & 127) * 4)) = o;
            } else {                              // W2 -> fp8 packed
                j -= n_mid;
                float4 v = ((const float4*)W2)[j];
                uchar4 o; o.x = f2fp8(v.x); o.y = f2fp8(v.y); o.z = f2fp8(v.z); o.w = f2fp8(v.w);
                *(uchar4*)(o_w28 + pack_addr(j >> 7, (j & 127) * 4)) = o;
            }
        }
    } else {
        // enorm: 8 rows per block, 2 per wave
        int w = tid >> 6, lane = tid & 63;
        int row0 = (bid - 1024) * 8 + w * 2;
        #pragma unroll
        for (int t = 0; t < 2; t++) {
            int row = row0 + t;
            const float4* p = (const float4*)(emb + (size_t)row * DIM) + lane * 2;
            float4 a = p[0], b = p[1];
            float s = a.x*a.x + a.y*a.y + a.z*a.z + a.w*a.w
                    + b.x*b.x + b.y*b.y + b.z*b.z + b.w*b.w;
            #pragma unroll
            for (int d = 1; d < 64; d <<= 1) s += __shfl_xor(s, d);
            if (lane == 0) enorm[row] = s;
        }
    }
}

// ---------------- h = LeakyReLU(eeg @ W1^T + b1): bf16 + packed fp8 out ----------------
__launch_bounds__(256, 2)
__global__ void k_hgemm(const unsigned short* __restrict__ A,
                        const unsigned short* __restrict__ B,
                        const float* __restrict__ b1,
                        unsigned short* __restrict__ H,
                        unsigned char* __restrict__ H8) {
    __shared__ __align__(16) unsigned short sA[4096], sB[4096];
    int tid = threadIdx.x;
    int w = tid >> 6, lane = tid & 63;
    int wr = w >> 1, wc = w & 1;
    int lquad = lane >> 4, l15 = lane & 15;
    int mt = blockIdx.x >> 2, nt = blockIdx.x & 3;
    int m0 = mt * 128, n0 = nt * 128;

    int e0 = w * 512 + lane * 8;
    int r0 = e0 >> 5, ce = e0 & 31;
    const unsigned short* gA0 = A + (m0 + r0) * DIM + ce;
    const unsigned short* gA1 = gA0 + 64 * DIM;
    const unsigned short* gB0 = B + (n0 + r0) * DIM + ce;
    const unsigned short* gB1 = gB0 + 64 * DIM;
    unsigned short* lA0 = sA + w * 512;  unsigned short* lA1 = sA + (w + 4) * 512;
    unsigned short* lB0 = sB + w * 512;  unsigned short* lB1 = sB + (w + 4) * 512;

    int offA[4], offB[4];
    #pragma unroll
    for (int i = 0; i < 4; i++) {
        offA[i] = (wr * 64 + i * 16 + l15) * 32 + lquad * 8;
        offB[i] = (wc * 64 + i * 16 + l15) * 32 + lquad * 8;
    }

    f32x4 acc[4][4];
    #pragma unroll
    for (int mi = 0; mi < 4; mi++)
        #pragma unroll
        for (int ni = 0; ni < 4; ni++) acc[mi][ni] = 0;

    for (int kk = 0; kk < 16; kk++) {
        gl_lds16(gA0, lA0); gl_lds16(gA1, lA1);
        gl_lds16(gB0, lB0); gl_lds16(gB1, lB1);
        gA0 += 32; gA1 += 32; gB0 += 32; gB1 += 32;
        __syncthreads();
        short8 af[4], bf_[4];
        #pragma unroll
        for (int i = 0; i < 4; i++) {
            af[i]  = *(const short8*)&sA[offA[i]];
            bf_[i] = *(const short8*)&sB[offB[i]];
        }
        #pragma unroll
        for (int mi = 0; mi < 4; mi++)
            #pragma unroll
            for (int ni = 0; ni < 4; ni++)
                acc[mi][ni] = __builtin_amdgcn_mfma_f32_16x16x32_bf16(af[mi], bf_[ni], acc[mi][ni], 0, 0, 0);
        __syncthreads();
    }

    #pragma unroll
    for (int ni = 0; ni < 4; ni++) {
        int col = n0 + wc * 64 + ni * 16 + l15;
        float bv = b1[col];
        #pragma unroll
        for (int mi = 0; mi < 4; mi++) {
            int rowb = m0 + wr * 64 + mi * 16 + lquad * 4;
            #pragma unroll
            for (int rg = 0; rg < 4; rg++) {
                float v = acc[mi][ni][rg] + bv;
                v = v >= 0.f ? v : NEG * v;
                H[(rowb + rg) * DIM + col] = f2bf(v);
                H8[pack_addr(rowb + rg, col)] = f2fp8(v);
            }
        }
    }
}

// ---------------- fat GEMM: even blocks = dist, odd blocks = logits ----------------
__launch_bounds__(256, 3)
__global__ void k_big(const unsigned char* __restrict__ Mel8,
                      const unsigned char* __restrict__ Emb8,
                      const unsigned char* __restrict__ H8,
                      const unsigned char* __restrict__ W28,
                      const float* __restrict__ enorm,
                      const float* __restrict__ b2,
                      float* __restrict__ p_s,
                      unsigned int* __restrict__ p_pmax,
                      unsigned int* __restrict__ p_pmin) {
    __shared__ __align__(16) unsigned char sA8[2][8192], sB8[2][8192];
    __shared__ float sAux[1024];
    __shared__ float red_s[256];
    __shared__ unsigned int red_pm[256];
    int tid = threadIdx.x;
    int w = tid >> 6, lane = tid & 63;
    int wr = w >> 1, wc = w & 1;
    int lquad = lane >> 4, l15 = lane & 15;
    int bid = blockIdx.x;
    int is_logits = bid & 1;
    int id = bid >> 1;
    int mt = id >> 3, split = id & 7;
    int m0 = mt * 128, nbase = split * (NEMB / NSPLIT);

    int uWd = w * 1024;  // wave-uniform LDS dst base (bytes)
    const unsigned char* gA8 = (is_logits ? H8 : Mel8) + (size_t)(m0 + 16 * w) * 512 + lane * 16;
    const unsigned char* gB8 = (is_logits ? W28 : Emb8) + (size_t)(nbase + 16 * w) * 512 + lane * 16;

    int offA[4], offB[4];
    #pragma unroll
    for (int i = 0; i < 4; i++) {
        offA[i] = (wr * 4 + i) * 1024 + lane * 16;
        offB[i] = (wc * 4 + i) * 1024 + lane * 16;
    }

    // stage aux table (enorm-512 for dist, b2 for logits) before any DMA
    #pragma unroll
    for (int j = 0; j < 4; j++) {
        int c = tid + j * 256;
        sAux[c] = is_logits ? b2[nbase + c] : (enorm[nbase + c] - 512.0f);
    }

    ISSUE8(0, 0);
    ISSUE8(1, 1);

    f32x4 acc[4][4];
    #pragma unroll
    for (int mi = 0; mi < 4; mi++)
        #pragma unroll
        for (int ni = 0; ni < 4; ni++) acc[mi][ni] = 0;

    float s[16];
    unsigned int pbest[16];
    unsigned int pinit = is_logits ? 0u : 0xFFFFFFFFu;
    #pragma unroll
    for (int r = 0; r < 16; r++) { s[r] = 0.f; pbest[r] = pinit; }

    for (int g = 0; g < NG; g += 2) {
        pipe_barrier();            // tile g's 4 loads done; g+1's stay in flight
        COMPUTE8(0);
        plain_barrier();
        ISSUE8(g + 2, 0);
        pipe_barrier();
        COMPUTE8(1);
        if (((g + 1) & 7) == 7) {
            int c0off = ((g + 1) >> 3) << 7;
            if (is_logits) {
                #pragma unroll
                for (int ni = 0; ni < 4; ni++) {
                    int j = c0off + wc * 64 + ni * 16 + l15;
                    float bb = sAux[j];
                    unsigned int ic = (unsigned int)(NEMB - 1 - (nbase + j));
                    #pragma unroll
                    for (int mi = 0; mi < 4; mi++)
                        #pragma unroll
                        for (int rg = 0; rg < 4; rg++) {
                            float logit = acc[mi][ni][rg] + bb;
                            int r = mi * 4 + rg;
                            s[r] += __expf(logit);     // logits are O(1): no max-shift needed
                            unsigned int pk = (fkey(logit) & 0xFFFFE000u) | ic;
                            pbest[r] = pbest[r] > pk ? pbest[r] : pk;
                            acc[mi][ni][rg] = 0.f;
                        }
                }
            } else {
                #pragma unroll
                for (int ni = 0; ni < 4; ni++) {
                    int j = c0off + wc * 64 + ni * 16 + l15;
                    float en = sAux[j];
                    unsigned int cl = (unsigned int)(nbase + j);
                    #pragma unroll
                    for (int mi = 0; mi < 4; mi++)
                        #pragma unroll
                        for (int rg = 0; rg < 4; rg++) {
                            float d = fmaf(-2.f, acc[mi][ni][rg], en);
                            unsigned int pk = (fkey(d) & 0xFFFFE000u) | cl;
                            int r = mi * 4 + rg;
                            pbest[r] = pbest[r] < pk ? pbest[r] : pk;
                            acc[mi][ni][rg] = 0.f;
                        }
                }
            }
        }
        plain_barrier();
        ISSUE8(g + 3, 1);
    }

    if (is_logits) {
        #pragma unroll
        for (int r = 0; r < 16; r++)
            #pragma unroll
            for (int d = 1; d < 16; d <<= 1) {
                s[r] += __shfl_xor(s[r], d);
                unsigned int o = (unsigned int)__shfl_xor((int)pbest[r], d);
                pbest[r] = pbest[r] > o ? pbest[r] : o;
            }
        if (l15 == 0) {
            #pragma unroll
            for (int mi = 0; mi < 4; mi++)
                #pragma unroll
                for (int rg = 0; rg < 4; rg++) {
                    int r2 = (wr * 64 + mi * 16 + lquad * 4 + rg) * 2 + wc;
                    red_s[r2] = s[mi * 4 + rg];
                    red_pm[r2] = pbest[mi * 4 + rg];
                }
        }
        __syncthreads();
        if (tid < 128) {
            float S = red_s[2 * tid] + red_s[2 * tid + 1];
            unsigned int a = red_pm[2 * tid], b = red_pm[2 * tid + 1];
            int pidx = split * BSZ + m0 + tid;
            p_s[pidx] = S;
            p_pmax[pidx] = a > b ? a : b;
        }
    } else {
        #pragma unroll
        for (int r = 0; r < 16; r++)
            #pragma unroll
            for (int d = 1; d < 16; d <<= 1) {
                unsigned int o = (unsigned int)__shfl_xor((int)pbest[r], d);
                pbest[r] = pbest[r] < o ? pbest[r] : o;
            }
        if (l15 == 0) {
            #pragma unroll
            for (int mi = 0; mi < 4; mi++)
                #pragma unroll
                for (int rg = 0; rg < 4; rg++)
                    red_pm[(wr * 64 + mi * 16 + lquad * 4 + rg) * 2 + wc] = pbest[mi * 4 + rg];
        }
        __syncthreads();
        if (tid < 128) {
            unsigned int a = red_pm[2 * tid], b = red_pm[2 * tid + 1];
            p_pmin[split * BSZ + m0 + tid] = a < b ? a : b;
        }
    }
}

// ---------------- tail: merge + gather + global reduce, writes d_out ----------------
__global__ void k_tail(const float* __restrict__ p_s, const unsigned int* __restrict__ p_pmax,
                       const unsigned int* __restrict__ p_pmin,
                       const unsigned short* __restrict__ H,
                       const float* __restrict__ W2,
                       const float* __restrict__ b2,
                       float* __restrict__ acc2, int* __restrict__ cnt,
                       float* __restrict__ out) {
    __shared__ int s_idx[256];
    __shared__ float s_l1[256], s_match[256];
    __shared__ float s_d[4];
    int bid = blockIdx.x, tid = threadIdx.x;
    int w = tid >> 6, lane = tid & 63;
    int r = bid * 256 + tid;

    // merge for own row
    float S = 0.f; unsigned int PM = 0u, PN = 0xFFFFFFFFu;
    #pragma unroll
    for (int sp = 0; sp < NSPLIT; sp++) {
        S += p_s[sp * BSZ + r];
        unsigned int a = p_pmax[sp * BSZ + r];
        PM = PM > a ? PM : a;
        unsigned int b = p_pmin[sp * BSZ + r];
        PN = PN < b ? PN : b;
    }
    int eidx = (NEMB - 1) - (int)(PM & 0x1FFFu);
    int midx = (int)(PN & 0x1FFFu);
    s_idx[tid] = midx;
    s_l1[tid] = __logf(S) - b2[midx];
    s_match[tid] = (eidx == midx) ? 1.f : 0.f;
    __syncthreads();

    // gather: wave w covers rows [w*64, w*64+64); pure per-lane dot partials
    float d0 = 0.f, d1 = 0.f;
    for (int j = 0; j < 64; j++) {
        int rr = w * 64 + j;
        int ridx = s_idx[rr];
        uint4 hv = *(const uint4*)(H + (size_t)(bid * 256 + rr) * DIM + lane * 8);
        const float4* wp = (const float4*)(W2 + (size_t)ridx * DIM + lane * 8);
        float4 w0 = wp[0], w1 = wp[1];
        float p = bf2f((unsigned short)(hv.x & 0xffff)) * w0.x + bf2f((unsigned short)(hv.x >> 16)) * w0.y
                + bf2f((unsigned short)(hv.y & 0xffff)) * w0.z + bf2f((unsigned short)(hv.y >> 16)) * w0.w
                + bf2f((unsigned short)(hv.z & 0xffff)) * w1.x + bf2f((unsigned short)(hv.z >> 16)) * w1.y
                + bf2f((unsigned short)(hv.w & 0xffff)) * w1.z + bf2f((unsigned short)(hv.w >> 16)) * w1.w;
        if (j & 1) d1 += p; else d0 += p;
    }
    float ds = d0 + d1;
    #pragma unroll
    for (int d = 1; d < 64; d <<= 1) ds += __shfl_xor(ds, d);
    if (lane == 0) s_d[w] = ds;

    __syncthreads();
    for (int st = 128; st > 0; st >>= 1) {
        if (tid < st) { s_l1[tid] += s_l1[tid + st]; s_match[tid] += s_match[tid + st]; }
        __syncthreads();
    }
    if (tid == 0) {
        float loss_blk = s_l1[0] - (s_d[0] + s_d[1] + s_d[2] + s_d[3]);
        atomicAdd(&acc2[0], loss_blk * (1.0f / BSZ));
        atomicAdd(&acc2[1], s_match[0] * (1.0f / BSZ));
        __threadfence();
        if (atomicAdd(cnt, 1) == 63) {
            float L = atomicAdd(&acc2[0], 0.f);
            float M = atomicAdd(&acc2[1], 0.f);
            out[0] = L; out[1] = M;
        }
    }
}

extern "C" void kernel_launch(void* const* d_in, const int* in_sizes, int n_in,
                              void* d_out, int out_size, void* d_ws, size_t ws_size,
                              hipStream_t stream) {
    const float* eeg = (const float*)d_in[0];
    const float* mel = (const float*)d_in[1];
    const float* emb = (const float*)d_in[2];
    const float* W1  = (const float*)d_in[3];
    const float* b1  = (const float*)d_in[4];
    const float* W2  = (const float*)d_in[5];
    const float* b2  = (const float*)d_in[6];
    float* out = (float*)d_out;

    unsigned short* ws_eeg = (unsigned short*)d_ws;               // BSZ*DIM bf16
    unsigned short* ws_w1  = ws_eeg + (size_t)BSZ * DIM;          // DIM*DIM bf16
    unsigned short* ws_h   = ws_w1  + (size_t)DIM * DIM;          // BSZ*DIM bf16
    unsigned char*  ws_h8  = (unsigned char*)(ws_h + (size_t)BSZ * DIM);
    unsigned char*  ws_mel8 = ws_h8  + (size_t)BSZ * DIM;
    unsigned char*  ws_emb8 = ws_mel8 + (size_t)BSZ * DIM;
    unsigned char*  ws_w28  = ws_emb8 + (size_t)NEMB * DIM;
    float* ws_en  = (float*)(ws_w28 + (size_t)NEMB * DIM);
    float* p_s    = ws_en + NEMB;
    unsigned int* p_pmax = (unsigned int*)(p_s + (size_t)NSPLIT * BSZ);
    unsigned int* p_pmin = p_pmax + (size_t)NSPLIT * BSZ;
    float* acc2   = (float*)(p_pmin + (size_t)NSPLIT * BSZ);
    int*   cnt    = (int*)(acc2 + 2);

    k_prep<<<2048, 256, 0, stream>>>(eeg, mel, emb, W2, W1,
                                     ws_eeg, ws_w1, ws_mel8, ws_emb8, ws_w28,
                                     ws_en, acc2, cnt);
    k_hgemm<<<(BSZ / 128) * (DIM / 128), 256, 0, stream>>>(ws_eeg, ws_w1, b1, ws_h, ws_h8);
    k_big<<<(BSZ / 128) * NSPLIT * 2, 256, 0, stream>>>(ws_mel8, ws_emb8, ws_h8, ws_w28,
                                                        ws_en, b2, p_s, p_pmax, p_pmin);
    k_tail<<<BSZ / 256, 256, 0, stream>>>(p_s, p_pmax, p_pmin, ws_h, W2, b2, acc2, cnt, out);
}